// Round 2
// baseline (582.375 us; speedup 1.0000x reference)
//
#include <hip/hip_runtime.h>

#define DIM 256
#define NT 64            // rows (w positions) per block
#define JT 64            // codebook entries per pass
#define NPASS 16
#define NELEM 8388608    // 8*256*64*64

// numpy pairwise sum of squares, 128-element block: 8 accumulators stride 8,
// combined ((r0+r1)+(r2+r3))+((r4+r5)+(r6+r7)). All ops single-rounded f32.
__device__ __forceinline__ float pw128_sq(const float* p, int s) {
  float r[8];
#pragma unroll
  for (int j = 0; j < 8; ++j) { float v = p[j * s]; r[j] = __fmul_rn(v, v); }
#pragma unroll
  for (int i = 8; i < 128; i += 8) {
#pragma unroll
    for (int j = 0; j < 8; ++j) {
      float v = p[(i + j) * s];
      r[j] = __fadd_rn(r[j], __fmul_rn(v, v));
    }
  }
  return __fadd_rn(__fadd_rn(__fadd_rn(r[0], r[1]), __fadd_rn(r[2], r[3])),
                   __fadd_rn(__fadd_rn(r[4], r[5]), __fadd_rn(r[6], r[7])));
}
// n=256: numpy recurses into 128+128, then adds the halves.
__device__ __forceinline__ float np_sumsq256(const float* p, int s) {
  return __fadd_rn(pw128_sq(p, s), pw128_sq(p + 128 * s, s));
}

__global__ __launch_bounds__(256)
void vq_kernel(const float* __restrict__ z, const float* __restrict__ cb,
               float* __restrict__ zq, float* __restrict__ loss,
               float* __restrict__ idxo) {
  __shared__ __align__(16) float zt[DIM * NT];    // [c][w]   64 KB
  __shared__ __align__(16) float cbt[DIM * JT];   // [c][jj]  64 KB (transposed)
  __shared__ float As[NT];                        // np-f32 ||z||^2 per row
  __shared__ float Bs[JT];                        // np-f32 ||e||^2 per tile code
  __shared__ int bestj[NT];
  __shared__ float cand_v[16 * NT];
  __shared__ int cand_i[16 * NT];
  __shared__ double wred[4];

  const int t = threadIdx.x;
  const int wg = t & 15;   // w = wg*4 + a
  const int jg = t >> 4;   // j = pass*64 + jg*4 + u
  const int bid = blockIdx.x;
  const int b = bid >> 6;
  const int h = bid & 63;
  const int n0 = bid * NT;

  // stage z tile: zt[c][w] = z[b][c][h][w]
  const float4* z4 = reinterpret_cast<const float4*>(z + (size_t)b * DIM * 4096 + (size_t)h * 64);
  float4* zt4 = reinterpret_cast<float4*>(zt);
#pragma unroll
  for (int i = 0; i < 16; ++i) {
    int idx4 = t + i * 256;
    int c = idx4 >> 4;
    int w4 = idx4 & 15;
    zt4[idx4] = z4[(size_t)c * 1024 + w4];
  }
  __syncthreads();
  if (t < NT) As[t] = np_sumsq256(zt + t, NT);   // row t, stride 64 over c

  float bv[4];
  int bi[4];
#pragma unroll
  for (int a = 0; a < 4; ++a) { bv[a] = 3.4e38f; bi[a] = 0; }

  for (int p = 0; p < NPASS; ++p) {
    __syncthreads();  // prev pass reads of cbt/Bs done; As ready (p==0)
    const float4* cb4 = reinterpret_cast<const float4*>(cb) + (size_t)p * JT * (DIM / 4);
#pragma unroll
    for (int i = 0; i < 16; ++i) {
      int idx4 = t + i * 256;        // jj*64 + c4
      int jj = idx4 >> 6;
      int c4 = idx4 & 63;
      float4 v = cb4[idx4];
      cbt[(c4 * 4 + 0) * JT + jj] = v.x;
      cbt[(c4 * 4 + 1) * JT + jj] = v.y;
      cbt[(c4 * 4 + 2) * JT + jj] = v.z;
      cbt[(c4 * 4 + 3) * JT + jj] = v.w;
    }
    __syncthreads();  // cbt ready

    if (t < JT) Bs[t] = np_sumsq256(cbt + t, JT);

    // C emulation: sequential f32 FMA over c ascending (OpenBLAS micro-kernel order)
    float acc[4][4];
#pragma unroll
    for (int a = 0; a < 4; ++a)
#pragma unroll
      for (int u = 0; u < 4; ++u) acc[a][u] = 0.0f;

    const float4* ztp = reinterpret_cast<const float4*>(zt) + wg;
    const float4* cbp = reinterpret_cast<const float4*>(cbt) + jg;
#pragma unroll 4
    for (int c = 0; c < DIM; ++c) {
      float4 zv = ztp[c * 16];
      float4 cv = cbp[c * 16];
      float za[4] = {zv.x, zv.y, zv.z, zv.w};
      float ca[4] = {cv.x, cv.y, cv.z, cv.w};
#pragma unroll
      for (int a = 0; a < 4; ++a)
#pragma unroll
        for (int u = 0; u < 4; ++u)
          acc[a][u] = fmaf(za[a], ca[u], acc[a][u]);
    }
    __syncthreads();  // Bs ready; cbt reads done

    // d = fl( fl(A + B) - 2*C ); ascending j per thread -> first-index ties kept
#pragma unroll
    for (int u = 0; u < 4; ++u) {
      int j = p * JT + jg * 4 + u;
      float Bju = Bs[jg * 4 + u];
#pragma unroll
      for (int a = 0; a < 4; ++a) {
        float AB = __fadd_rn(As[wg * 4 + a], Bju);
        float dd = __fsub_rn(AB, __fmul_rn(2.0f, acc[a][u]));
        if (dd < bv[a]) { bv[a] = dd; bi[a] = j; }
      }
    }
  }

  __syncthreads();
#pragma unroll
  for (int a = 0; a < 4; ++a) {
    int w = wg * 4 + a;
    cand_v[jg * NT + w] = bv[a];
    cand_i[jg * NT + w] = bi[a];
  }
  __syncthreads();
  if (t < NT) {
    float v0 = cand_v[t];
    int i0 = cand_i[t];
    for (int g = 1; g < 16; ++g) {
      float v = cand_v[g * NT + t];
      int ii = cand_i[g * NT + t];
      if (v < v0 || (v == v0 && ii < i0)) { v0 = v; i0 = ii; }
    }
    bestj[t] = i0;
    idxo[n0 + t] = (float)i0;
  }
  __syncthreads();

  // z_q write + loss partial (thresholds on these are loose; keep exact-ish)
  double lsum = 0.0;
  float* zqbase = zq + (size_t)b * DIM * 4096 + (size_t)h * 64;
  for (int i = 0; i < 64; ++i) {
    int idx = t + i * 256;
    int c = idx >> 6;
    int w = idx & 63;
    float zvv = zt[c * NT + w];
    float cvv = cb[(size_t)bestj[w] * DIM + c];
    zqbase[(size_t)c * 4096 + w] = cvv;
    double d = (double)cvv - (double)zvv;
    lsum += d * d;
  }
#pragma unroll
  for (int off = 32; off > 0; off >>= 1) lsum += __shfl_down(lsum, off, 64);
  if ((t & 63) == 0) wred[t >> 6] = lsum;
  __syncthreads();
  if (t == 0) {
    double tot = wred[0] + wred[1] + wred[2] + wred[3];
    atomicAdd(loss, (float)(tot * (1.25 / (double)NELEM)));
  }
}

extern "C" void kernel_launch(void* const* d_in, const int* in_sizes, int n_in,
                              void* d_out, int out_size, void* d_ws, size_t ws_size,
                              hipStream_t stream) {
  const float* z = (const float*)d_in[0];
  const float* cb = (const float*)d_in[1];
  float* out = (float*)d_out;
  float* zq = out;                   // 8388608
  float* loss = out + NELEM;         // 1
  float* idxo = out + NELEM + 1;     // 32768 (as float)
  hipMemsetAsync(loss, 0, sizeof(float), stream);
  vq_kernel<<<512, 256, 0, stream>>>(z, cb, zq, loss, idxo);
}